// Round 7
// baseline (189.684 us; speedup 1.0000x reference)
//
#include <hip/hip_runtime.h>
#include <stdint.h>

typedef unsigned long long u64;
typedef unsigned int u32;
typedef unsigned short u16;

#define NBINS 512
#define CAP 512          // max candidates per head (count-cap rule)
#define POOLCAP 2048     // >= W*CAP: pool provably contains all heads' candidates
#define LOG_CUT (-64.0f)
#define LOG_SCALE 20.0f
#define NT 512

// ---------------- Kernel A: streaming usage + zero-fill alloc ----------------
// usage = (prev + (1-prev)*(1-prod_w(1-ww))) * prod_r(1-fg*rw), bit-exact f32.
// Round-3-validated structure (grid-stride, high occupancy, pure streams).
template <int TW, int TR>
__global__ __launch_bounds__(256)
void phaseA_kernel(const float* __restrict__ ww, const float* __restrict__ fg,
                   const float* __restrict__ rw, const float* __restrict__ prev,
                   float* __restrict__ out_usage, float* __restrict__ out_alloc,
                   int B, int W, int R, int M)
{
    const int Wl = TW > 0 ? TW : W;
    const int Rl = TR > 0 ? TR : R;
    const int g4 = M >> 2;
    const long long total = (long long)B * g4;
    const long long stride = (long long)gridDim.x * blockDim.x;
    for (long long g = (long long)blockIdx.x * blockDim.x + threadIdx.x; g < total; g += stride) {
        const int b = (int)(g / g4);
        const int m = ((int)(g % g4)) << 2;
        const size_t bM = (size_t)b * M + m;
        const float4 pv = *(const float4*)(prev + bM);
        float pr0 = 1.f, pr1 = 1.f, pr2 = 1.f, pr3 = 1.f;
        #pragma unroll
        for (int w = 0; w < Wl; ++w) {
            const float4 a = *(const float4*)(ww + ((size_t)b * Wl + w) * M + m);
            pr0 *= (1.0f - a.x); pr1 *= (1.0f - a.y);
            pr2 *= (1.0f - a.z); pr3 *= (1.0f - a.w);
        }
        float u0 = pv.x + (1.0f - pv.x) * (1.0f - pr0);
        float u1 = pv.y + (1.0f - pv.y) * (1.0f - pr1);
        float u2 = pv.z + (1.0f - pv.z) * (1.0f - pr2);
        float u3 = pv.w + (1.0f - pv.w) * (1.0f - pr3);
        float f0 = 1.f, f1 = 1.f, f2 = 1.f, f3 = 1.f;
        #pragma unroll
        for (int r = 0; r < Rl; ++r) {
            const float fr = fg[(size_t)b * Rl + r];
            const float4 a = *(const float4*)(rw + ((size_t)b * Rl + r) * M + m);
            f0 *= (1.0f - fr * a.x); f1 *= (1.0f - fr * a.y);
            f2 *= (1.0f - fr * a.z); f3 *= (1.0f - fr * a.w);
        }
        float4 uo;
        uo.x = u0 * f0; uo.y = u1 * f1; uo.z = u2 * f2; uo.w = u3 * f3;
        *(float4*)(out_usage + bM) = uo;
        const float4 z = make_float4(0.f, 0.f, 0.f, 0.f);
        #pragma unroll
        for (int w = 0; w < Wl; ++w)
            *(float4*)(out_alloc + ((size_t)b * Wl + w) * M + m) = z;
    }
}

// ---------------- Kernel B: per-row allocation via 2048-element pool ----------------
// Pool built once per row; per head: pool-local hist -> exact-mass suffix scan ->
// bucket-grouped rank (suffix mass + same-bucket key compares) -> sparse scatter.
// All bucketing/logs from ue_b = 1-(1-ue): bucket is a pure function of the sort
// key, making the grouped rank EXACTLY equal to full key-order rank.
__global__ __launch_bounds__(NT, 4)
void phaseB_kernel(const float* __restrict__ wgt,
                   const float* __restrict__ usage_in,   // [B,M]
                   float* __restrict__ out_alloc,        // [B,W,M], pre-zeroed by A
                   int B, int W, int M)
{
    __shared__ float poolU[POOLCAP];    // raw usage, updated per head
    __shared__ u16   poolIdx[POOLCAP];
    __shared__ float poolLg[POOLCAP];   // per-head log2(ue_b)
    __shared__ u32   hC[NBINS];
    __shared__ float hL[NBINS];
    __shared__ u32   cntAb[NBINS];      // count in buckets strictly above
    __shared__ float masAb[NBINS];      // mass  in buckets strictly above
    __shared__ u32   grpFill[NBINS];
    __shared__ u64   candKey[CAP];
    __shared__ float candLg[CAP];
    __shared__ u16   candPos[CAP];
    __shared__ u16   candBkt[CAP];
    __shared__ u32   tc[8];
    __shared__ float twv[8];
    __shared__ int   misc[4];           // [0]=pool count, [1]=xs, [2]=xc, [3]=pc

    const int b = blockIdx.x;
    const int t = threadIdx.x;
    const int lane = t & 63;
    const int wid = t >> 6;

    const float C1 = (float)(1.0 - 1e-6);
    const float CE = 1e-6f;
    const float* U = usage_in + (size_t)b * M;

    // ---- pass 1: full-row count histogram (bucket from ue_b) ----
    hC[t] = 0u;
    if (t == 0) { misc[0] = 0; misc[3] = NBINS; }
    __syncthreads();
    for (int m = t; m < M; m += NT) {
        const float u = U[m];
        const float ue = CE + C1 * u;
        const float nn = 1.0f - ue;      // nonusage exactly as ref
        const float ueb = 1.0f - nn;     // = ref's sorted_usage value
        const float lg = __log2f(ueb);
        int bkt = (int)(-lg * LOG_SCALE);
        bkt = bkt < 0 ? 0 : (bkt > NBINS - 1 ? NBINS - 1 : bkt);
        atomicAdd(&hC[bkt], 1u);
    }
    __syncthreads();

    // ---- pool cut: min x with suffix-count <= POOLCAP ----
    {
        const int x = NBINS - 1 - t;
        u32 sc = hC[x];
        #pragma unroll
        for (int off = 1; off < 64; off <<= 1) {
            const u32 oc = __shfl_up(sc, off);
            if (lane >= off) sc += oc;
        }
        if (lane == 63) tc[wid] = sc;
        __syncthreads();
        u32 ac = 0;
        for (int q = 0; q < wid; ++q) ac += tc[q];
        sc += ac;
        if (sc <= (u32)POOLCAP) atomicMin(&misc[3], x);
    }
    __syncthreads();
    const int pc = misc[3];

    // ---- pass 2: compact pool (bkt >= pc) ----
    for (int m = t; m < M; m += NT) {
        const float u = U[m];
        const float ue = CE + C1 * u;
        const float nn = 1.0f - ue;
        const float ueb = 1.0f - nn;
        const float lg = __log2f(ueb);
        int bkt = (int)(-lg * LOG_SCALE);
        bkt = bkt < 0 ? 0 : (bkt > NBINS - 1 ? NBINS - 1 : bkt);
        const bool pred = (bkt >= pc) && (pc < NBINS);
        const u64 mask = __ballot(pred);
        const int cnt = __popcll(mask);
        if (cnt) {
            int base = 0;
            if (lane == 0) base = atomicAdd(&misc[0], cnt);
            base = __shfl(base, 0);
            if (pred) {
                const int pos = base + __popcll(mask & ((1ull << lane) - 1));
                if (pos < POOLCAP) { poolU[pos] = u; poolIdx[pos] = (u16)m; }
            }
        }
    }
    __syncthreads();
    int P = misc[0]; if (P > POOLCAP) P = POOLCAP;

    // ---- heads ----
    for (int i = 0; i < W; ++i) {
        const float wgi = wgt[(size_t)b * W + i];
        float* orow = out_alloc + ((size_t)b * W + i) * M;

        hC[t] = 0u; hL[t] = 0.0f; grpFill[t] = 0u;
        if (t < CAP) candKey[t] = ~0ull;
        if (t == 0) { misc[1] = -1; misc[2] = NBINS; }
        __syncthreads();

        // pool-local histogram with exact per-bucket log-mass
        for (int p = t; p < P; p += NT) {
            const float u = poolU[p];
            const float ue = CE + C1 * u;
            const float nn = 1.0f - ue;
            const float ueb = 1.0f - nn;
            const float lg = __log2f(ueb);
            poolLg[p] = lg;
            int bkt = (int)(-lg * LOG_SCALE);
            bkt = bkt < 0 ? 0 : (bkt > NBINS - 1 ? NBINS - 1 : bkt);
            atomicAdd(&hC[bkt], 1u);
            atomicAdd(&hL[bkt], lg);
        }
        __syncthreads();

        // suffix scan (thread t owns x = NBINS-1-t): exact counts and mass.
        // Conditions gated to x >= pc (pool-hist == full-row hist there; proven
        // that true head cuts never fall below pc).
        {
            const int x = NBINS - 1 - t;
            const u32 c = hC[x];
            const float w0 = hL[x];
            u32 sc = c; float sw = w0;
            #pragma unroll
            for (int off = 1; off < 64; off <<= 1) {
                const u32  oc = __shfl_up(sc, off);
                const float ow = __shfl_up(sw, off);
                if (lane >= off) { sc += oc; sw += ow; }
            }
            if (lane == 63) { tc[wid] = sc; twv[wid] = sw; }
            __syncthreads();
            u32 ac = 0; float aw = 0.f;
            for (int q = 0; q < wid; ++q) { ac += tc[q]; aw += twv[q]; }
            sc += ac; sw += aw;
            cntAb[x] = sc - c;       // strictly-above count
            masAb[x] = sw - w0;      // strictly-above mass
            if (x >= pc) {
                if (sw <= LOG_CUT)  atomicMax(&misc[1], x);  // xs: exact-mass cut
                if (sc <= (u32)CAP) atomicMin(&misc[2], x);  // xc: count cap
            }
        }
        __syncthreads();
        const int xs = misc[1], xc = misc[2];
        const int cut = xs > xc ? xs : xc;
        int K = 0;
        if (cut < NBINS) K = (int)(cntAb[cut] + hC[cut]);
        if (K > CAP) K = CAP;

        // candidate select -> bucket-grouped slots (slot = cntAb[bkt] + fill)
        for (int p = t; p < P; p += NT) {
            const float lg = poolLg[p];
            int bkt = (int)(-lg * LOG_SCALE);
            bkt = bkt < 0 ? 0 : (bkt > NBINS - 1 ? NBINS - 1 : bkt);
            if (cut < NBINS && bkt >= cut) {
                const float u = poolU[p];
                const float ue = CE + C1 * u;
                const float nn = 1.0f - ue;
                const u64 key = (((u64)(~__float_as_uint(nn))) << 16) | (u64)poolIdx[p];
                const int slot = (int)cntAb[bkt] + (int)atomicAdd(&grpFill[bkt], 1u);
                if (slot < CAP) {
                    candKey[slot] = key; candLg[slot] = lg;
                    candPos[slot] = (u16)p; candBkt[slot] = (u16)bkt;
                }
            }
        }
        __syncthreads();

        // grouped rank: S = mass(buckets above) + sum over same-bucket smaller keys.
        // key asc == nonusage desc with low-index tiebreak (== lax.top_k order);
        // bucket is a monotone function of key -> exactly equals full-order rank.
        if (t < K) {
            const u64 key = candKey[t];
            const int bkt = (int)candBkt[t];
            float S = masAb[bkt];
            const int g0 = (int)cntAb[bkt];
            const int gn = (int)hC[bkt];
            for (int j = g0; j < g0 + gn; ++j) {
                if (candKey[j] < key) S += candLg[j];
            }
            const float nn = __uint_as_float(~((u32)(key >> 16)));
            const int idx = (int)(key & 0xFFFFull);
            const float al = nn * __builtin_exp2f(S);
            if (al != 0.0f) {
                orow[idx] = al;                       // row pre-zeroed by kernel A
                const int p = (int)candPos[t];
                const float u0 = poolU[p];
                poolU[p] = u0 + ((1.0f - u0) * wgi) * al;   // ref's usage update
            }
        }
        __syncthreads();
    }
}

extern "C" void kernel_launch(void* const* d_in, const int* in_sizes, int n_in,
                              void* d_out, int out_size, void* d_ws, size_t ws_size,
                              hipStream_t stream) {
    const float* ww   = (const float*)d_in[0];
    const float* fg   = (const float*)d_in[1];
    const float* rw   = (const float*)d_in[2];
    const float* prev = (const float*)d_in[3];
    const float* wgt  = (const float*)d_in[4];
    const int BWM = in_sizes[0];
    const int BR  = in_sizes[1];
    const int BM  = in_sizes[3];
    const int BW  = in_sizes[4];
    const int M = BWM / BW;
    const int B = BM / M;
    const int W = BW / B;
    const int R = BR / B;

    float* out_usage = (float*)d_out;
    float* out_alloc = out_usage + (size_t)BM;

    // Kernel A: streaming usage + zero-fill (round-3-validated structure)
    const long long granules = (long long)B * (M >> 2);
    int blocks = (int)((granules + 255) / 256);
    if (blocks > 2048) blocks = 2048;
    if (W == 4 && R == 8) {
        hipLaunchKernelGGL((phaseA_kernel<4, 8>), dim3(blocks), dim3(256), 0, stream,
                           ww, fg, rw, prev, out_usage, out_alloc, B, W, R, M);
    } else {
        hipLaunchKernelGGL((phaseA_kernel<0, 0>), dim3(blocks), dim3(256), 0, stream,
                           ww, fg, rw, prev, out_usage, out_alloc, B, W, R, M);
    }

    // Kernel B: pool-based allocation (scatter-only global writes)
    hipLaunchKernelGGL(phaseB_kernel, dim3(B), dim3(NT), 0, stream,
                       wgt, out_usage, out_alloc, B, W, M);
}

// Round 8
// 168.998 us; speedup vs baseline: 1.1224x; 1.1224x over previous
//
#include <hip/hip_runtime.h>
#include <stdint.h>

typedef unsigned long long u64;
typedef unsigned int u32;
typedef unsigned short u16;

#define NBINS 512
#define CAP 512          // max candidates per head (count-cap rule)
#define POOLCAP 2048     // >= W*CAP: pool provably contains all heads' candidates
#define LOG_CUT (-64.0f)
#define LOG_SCALE 20.0f
#define NT 512

// One fused kernel, one workgroup per batch row.
// Phase S: stream inputs -> usage (bit-exact f32, held in REGISTERS) -> global;
//          zero-fill alloc rows; build bucket count-hist inline (once).
// Pool: cut scan -> compact 2048 smallest-usage elements from registers.
// Phase H (x W heads): pool-local hist (exact log mass) -> suffix scan ->
//   bucket-grouped rank (== full key-order rank) -> sparse scatter + pool update.
// LDS ~39KB static, no dynamic. Grid = B blocks (2/CU).
template <int TW, int TR, int GPT>   // GPT = M/(4*NT); 0 = generic fallback
__global__ __launch_bounds__(NT, 4)
void fused_kernel(const float* __restrict__ ww,    // [B,W,M]
                  const float* __restrict__ fg,    // [B,R]
                  const float* __restrict__ rw,    // [B,R,M]
                  const float* __restrict__ prev,  // [B,M]
                  const float* __restrict__ wgt,   // [B,W]
                  float* __restrict__ out_usage,   // [B,M]
                  float* __restrict__ out_alloc,   // [B,W,M]
                  int B, int W, int R, int M)
{
    __shared__ float poolU[POOLCAP];
    __shared__ u16   poolIdx[POOLCAP];
    __shared__ float poolLg[POOLCAP];
    __shared__ u32   hC[NBINS];
    __shared__ float hL[NBINS];
    __shared__ u32   cntAb[NBINS];
    __shared__ float masAb[NBINS];
    __shared__ u32   grpFill[NBINS];
    __shared__ u64   candKey[CAP];
    __shared__ float candLg[CAP];
    __shared__ u16   candPos[CAP];
    __shared__ u16   candBkt[CAP];
    __shared__ u32   tc[8];
    __shared__ float twv[8];
    __shared__ int   misc[4];       // [0]=pool count, [1]=xs, [2]=xc, [3]=pc

    const int Wl = TW > 0 ? TW : W;
    const int Rl = TR > 0 ? TR : R;
    const int b = blockIdx.x;
    const int t = threadIdx.x;
    const int lane = t & 63;
    const int wid = t >> 6;

    const float C1 = (float)(1.0 - 1e-6);
    const float CE = 1e-6f;
    const size_t rowOff = (size_t)b * M;

    hC[t] = 0u;
    if (t == 0) { misc[0] = 0; misc[3] = NBINS; }
    __syncthreads();

    // ---------------- Phase S: streaming + inline histogram ----------------
    // usage = (prev + (1-prev)*(1-prod_w(1-ww))) * prod_r(1-fg*rw), ref f32 op order
    float4 ureg[GPT > 0 ? GPT : 1];
    {
        const float* wp0 = ww + (size_t)b * Wl * M;
        const float* rp0 = rw + (size_t)b * Rl * M;
        float frs[TR > 0 ? TR : 8];
        #pragma unroll
        for (int r = 0; r < Rl; ++r) frs[r] = fg[(size_t)b * Rl + r];
        const float4 z = make_float4(0.f, 0.f, 0.f, 0.f);

        #pragma unroll
        for (int k = 0; k < (GPT > 0 ? GPT : 0); ++k) {
            const int m = (t + k * NT) * 4;
            const float4 pv = *(const float4*)(prev + rowOff + m);
            float pr0 = 1.f, pr1 = 1.f, pr2 = 1.f, pr3 = 1.f;
            #pragma unroll
            for (int w = 0; w < Wl; ++w) {
                const float4 a = *(const float4*)(wp0 + (size_t)w * M + m);
                pr0 *= (1.0f - a.x); pr1 *= (1.0f - a.y);
                pr2 *= (1.0f - a.z); pr3 *= (1.0f - a.w);
            }
            float u0 = pv.x + (1.0f - pv.x) * (1.0f - pr0);
            float u1 = pv.y + (1.0f - pv.y) * (1.0f - pr1);
            float u2 = pv.z + (1.0f - pv.z) * (1.0f - pr2);
            float u3 = pv.w + (1.0f - pv.w) * (1.0f - pr3);
            float f0 = 1.f, f1 = 1.f, f2 = 1.f, f3 = 1.f;
            #pragma unroll
            for (int r = 0; r < Rl; ++r) {
                const float fr = frs[r];
                const float4 a = *(const float4*)(rp0 + (size_t)r * M + m);
                f0 *= (1.0f - fr * a.x); f1 *= (1.0f - fr * a.y);
                f2 *= (1.0f - fr * a.z); f3 *= (1.0f - fr * a.w);
            }
            float4 uo;
            uo.x = u0 * f0; uo.y = u1 * f1; uo.z = u2 * f2; uo.w = u3 * f3;
            ureg[k] = uo;
            *(float4*)(out_usage + rowOff + m) = uo;
            #pragma unroll
            for (int w = 0; w < Wl; ++w)
                *(float4*)(out_alloc + ((size_t)b * Wl + w) * M + m) = z;
            const float ua[4] = {uo.x, uo.y, uo.z, uo.w};
            #pragma unroll
            for (int j = 0; j < 4; ++j) {
                const float ue = CE + C1 * ua[j];
                const float nn = 1.0f - ue;
                const float lg = __log2f(1.0f - nn);   // log2(ue_b): key-pure bucket
                int bkt = (int)(-lg * LOG_SCALE);
                bkt = bkt < 0 ? 0 : (bkt > NBINS - 1 ? NBINS - 1 : bkt);
                atomicAdd(&hC[bkt], 1u);
            }
        }
        if (GPT == 0) {   // generic fallback: no register cache
            for (int m = t * 4; m < M; m += NT * 4) {
                const float4 pv = *(const float4*)(prev + rowOff + m);
                float pr0 = 1.f, pr1 = 1.f, pr2 = 1.f, pr3 = 1.f;
                for (int w = 0; w < Wl; ++w) {
                    const float4 a = *(const float4*)(wp0 + (size_t)w * M + m);
                    pr0 *= (1.0f - a.x); pr1 *= (1.0f - a.y);
                    pr2 *= (1.0f - a.z); pr3 *= (1.0f - a.w);
                }
                float u0 = pv.x + (1.0f - pv.x) * (1.0f - pr0);
                float u1 = pv.y + (1.0f - pv.y) * (1.0f - pr1);
                float u2 = pv.z + (1.0f - pv.z) * (1.0f - pr2);
                float u3 = pv.w + (1.0f - pv.w) * (1.0f - pr3);
                float f0 = 1.f, f1 = 1.f, f2 = 1.f, f3 = 1.f;
                for (int r = 0; r < Rl; ++r) {
                    const float fr = frs[r];
                    const float4 a = *(const float4*)(rp0 + (size_t)r * M + m);
                    f0 *= (1.0f - fr * a.x); f1 *= (1.0f - fr * a.y);
                    f2 *= (1.0f - fr * a.z); f3 *= (1.0f - fr * a.w);
                }
                float4 uo;
                uo.x = u0 * f0; uo.y = u1 * f1; uo.z = u2 * f2; uo.w = u3 * f3;
                *(float4*)(out_usage + rowOff + m) = uo;
                const float ua[4] = {uo.x, uo.y, uo.z, uo.w};
                for (int j = 0; j < 4; ++j) {
                    const float ue = CE + C1 * ua[j];
                    const float nn = 1.0f - ue;
                    const float lg = __log2f(1.0f - nn);
                    int bkt = (int)(-lg * LOG_SCALE);
                    bkt = bkt < 0 ? 0 : (bkt > NBINS - 1 ? NBINS - 1 : bkt);
                    atomicAdd(&hC[bkt], 1u);
                }
                const float4 z2 = make_float4(0.f, 0.f, 0.f, 0.f);
                for (int w = 0; w < Wl; ++w)
                    *(float4*)(out_alloc + ((size_t)b * Wl + w) * M + m) = z2;
            }
        }
    }
    __syncthreads();

    // ---------------- Pool cut: min x with suffix-count <= POOLCAP ----------------
    {
        const int x = NBINS - 1 - t;
        u32 sc = hC[x];
        #pragma unroll
        for (int off = 1; off < 64; off <<= 1) {
            const u32 oc = __shfl_up(sc, off);
            if (lane >= off) sc += oc;
        }
        if (lane == 63) tc[wid] = sc;
        __syncthreads();
        u32 ac = 0;
        for (int q = 0; q < wid; ++q) ac += tc[q];
        sc += ac;
        if (sc <= (u32)POOLCAP) atomicMin(&misc[3], x);
    }
    __syncthreads();
    const int pc = misc[3];

    // ---------------- Pool compact (from registers / global fallback) ----------------
    if (GPT > 0) {
        #pragma unroll
        for (int k = 0; k < (GPT > 0 ? GPT : 1); ++k) {
            const float ua[4] = {ureg[k].x, ureg[k].y, ureg[k].z, ureg[k].w};
            #pragma unroll
            for (int j = 0; j < 4; ++j) {
                const int m = (t + k * NT) * 4 + j;
                const float u = ua[j];
                const float ue = CE + C1 * u;
                const float nn = 1.0f - ue;
                const float lg = __log2f(1.0f - nn);
                int bkt = (int)(-lg * LOG_SCALE);
                bkt = bkt < 0 ? 0 : (bkt > NBINS - 1 ? NBINS - 1 : bkt);
                const bool pred = (bkt >= pc) && (pc < NBINS);
                const u64 mask = __ballot(pred);
                const int cnt = __popcll(mask);
                if (cnt) {
                    int base = 0;
                    if (lane == 0) base = atomicAdd(&misc[0], cnt);
                    base = __shfl(base, 0);
                    if (pred) {
                        const int pos = base + __popcll(mask & ((1ull << lane) - 1));
                        if (pos < POOLCAP) { poolU[pos] = u; poolIdx[pos] = (u16)m; }
                    }
                }
            }
        }
    } else {
        for (int m = t; m < M; m += NT) {
            const float u = out_usage[rowOff + m];   // visible: post-__syncthreads
            const float ue = CE + C1 * u;
            const float nn = 1.0f - ue;
            const float lg = __log2f(1.0f - nn);
            int bkt = (int)(-lg * LOG_SCALE);
            bkt = bkt < 0 ? 0 : (bkt > NBINS - 1 ? NBINS - 1 : bkt);
            const bool pred = (bkt >= pc) && (pc < NBINS);
            const u64 mask = __ballot(pred);
            const int cnt = __popcll(mask);
            if (cnt) {
                int base = 0;
                if (lane == 0) base = atomicAdd(&misc[0], cnt);
                base = __shfl(base, 0);
                if (pred) {
                    const int pos = base + __popcll(mask & ((1ull << lane) - 1));
                    if (pos < POOLCAP) { poolU[pos] = u; poolIdx[pos] = (u16)m; }
                }
            }
        }
    }
    __syncthreads();
    int P = misc[0]; if (P > POOLCAP) P = POOLCAP;

    // ---------------- Phase H: per write head (pool-only) ----------------
    for (int i = 0; i < Wl; ++i) {
        const float wgi = wgt[(size_t)b * Wl + i];
        float* orow = out_alloc + ((size_t)b * Wl + i) * M;

        hC[t] = 0u; hL[t] = 0.0f; grpFill[t] = 0u;
        if (t < CAP) candKey[t] = ~0ull;
        if (t == 0) { misc[1] = -1; misc[2] = NBINS; }
        __syncthreads();

        // pool-local histogram with exact per-bucket log-mass
        for (int p = t; p < P; p += NT) {
            const float u = poolU[p];
            const float ue = CE + C1 * u;
            const float nn = 1.0f - ue;
            const float lg = __log2f(1.0f - nn);
            poolLg[p] = lg;
            int bkt = (int)(-lg * LOG_SCALE);
            bkt = bkt < 0 ? 0 : (bkt > NBINS - 1 ? NBINS - 1 : bkt);
            atomicAdd(&hC[bkt], 1u);
            atomicAdd(&hL[bkt], lg);
        }
        __syncthreads();

        // suffix scan (thread t owns x = NBINS-1-t): exact counts and mass;
        // xs/xc gated to x >= pc (pool-hist == full-row hist there)
        {
            const int x = NBINS - 1 - t;
            const u32 c = hC[x];
            const float w0 = hL[x];
            u32 sc = c; float sw = w0;
            #pragma unroll
            for (int off = 1; off < 64; off <<= 1) {
                const u32  oc = __shfl_up(sc, off);
                const float ow = __shfl_up(sw, off);
                if (lane >= off) { sc += oc; sw += ow; }
            }
            if (lane == 63) { tc[wid] = sc; twv[wid] = sw; }
            __syncthreads();
            u32 ac = 0; float aw = 0.f;
            for (int q = 0; q < wid; ++q) { ac += tc[q]; aw += twv[q]; }
            sc += ac; sw += aw;
            cntAb[x] = sc - c;
            masAb[x] = sw - w0;
            if (x >= pc) {
                if (sw <= LOG_CUT)  atomicMax(&misc[1], x);
                if (sc <= (u32)CAP) atomicMin(&misc[2], x);
            }
        }
        __syncthreads();
        const int xs = misc[1], xc = misc[2];
        const int cut = xs > xc ? xs : xc;
        int K = 0;
        if (cut < NBINS) K = (int)(cntAb[cut] + hC[cut]);
        if (K > CAP) K = CAP;

        // candidate select -> bucket-grouped slots (slot = cntAb[bkt] + fill)
        for (int p = t; p < P; p += NT) {
            const float lg = poolLg[p];
            int bkt = (int)(-lg * LOG_SCALE);
            bkt = bkt < 0 ? 0 : (bkt > NBINS - 1 ? NBINS - 1 : bkt);
            if (cut < NBINS && bkt >= cut) {
                const float u = poolU[p];
                const float ue = CE + C1 * u;
                const float nn = 1.0f - ue;
                const u64 key = (((u64)(~__float_as_uint(nn))) << 16) | (u64)poolIdx[p];
                const int slot = (int)cntAb[bkt] + (int)atomicAdd(&grpFill[bkt], 1u);
                if (slot < CAP) {
                    candKey[slot] = key; candLg[slot] = lg;
                    candPos[slot] = (u16)p; candBkt[slot] = (u16)bkt;
                }
            }
        }
        __syncthreads();

        // grouped rank == full key-order rank (bucket monotone in key)
        if (t < K) {
            const u64 key = candKey[t];
            const int bkt = (int)candBkt[t];
            float S = masAb[bkt];
            const int g0 = (int)cntAb[bkt];
            const int gn = (int)hC[bkt];
            for (int j = g0; j < g0 + gn; ++j) {
                if (candKey[j] < key) S += candLg[j];
            }
            const float nn = __uint_as_float(~((u32)(key >> 16)));
            const int idx = (int)(key & 0xFFFFull);
            const float al = nn * __builtin_exp2f(S);
            if (al != 0.0f) {
                orow[idx] = al;                       // row pre-zeroed in phase S
                const int p = (int)candPos[t];
                const float u0 = poolU[p];
                poolU[p] = u0 + ((1.0f - u0) * wgi) * al;   // ref's usage update
            }
        }
        __syncthreads();
    }
}

extern "C" void kernel_launch(void* const* d_in, const int* in_sizes, int n_in,
                              void* d_out, int out_size, void* d_ws, size_t ws_size,
                              hipStream_t stream) {
    const float* ww   = (const float*)d_in[0];
    const float* fg   = (const float*)d_in[1];
    const float* rw   = (const float*)d_in[2];
    const float* prev = (const float*)d_in[3];
    const float* wgt  = (const float*)d_in[4];
    const int BWM = in_sizes[0];
    const int BR  = in_sizes[1];
    const int BM  = in_sizes[3];
    const int BW  = in_sizes[4];
    const int M = BWM / BW;
    const int B = BM / M;
    const int W = BW / B;
    const int R = BR / B;

    float* out_usage = (float*)d_out;
    float* out_alloc = out_usage + (size_t)BM;

    if (W == 4 && R == 8 && M == NT * 4 * 8) {
        hipLaunchKernelGGL((fused_kernel<4, 8, 8>), dim3(B), dim3(NT), 0, stream,
                           ww, fg, rw, prev, wgt, out_usage, out_alloc, B, W, R, M);
    } else {
        hipLaunchKernelGGL((fused_kernel<0, 0, 0>), dim3(B), dim3(NT), 0, stream,
                           ww, fg, rw, prev, wgt, out_usage, out_alloc, B, W, R, M);
    }
}